// Round 10
// baseline (237.552 us; speedup 1.0000x reference)
//
#include <hip/hip_runtime.h>
#include <hip/hip_bf16.h>

typedef unsigned short ushort_t;
typedef unsigned int uint_t;
typedef __attribute__((ext_vector_type(8))) short short8;
typedef __attribute__((ext_vector_type(4))) float floatx4;

#define QSCALE 0.03187936f  // (1/sqrt(2048)) * log2(e): quirk scale + exp2 fold

__device__ __forceinline__ ushort_t f2bf(float f) {
    union { float f; uint_t u; } c; c.f = f;
    uint_t u = c.u;
    return (ushort_t)((u + 0x7fffu + ((u >> 16) & 1u)) >> 16);  // RNE
}
__device__ __forceinline__ uint_t pack_bf2(float a, float b) {
    union { __hip_bfloat162 h; uint_t u; } c;
    c.h = __float22bfloat162_rn(make_float2(a, b));  // v_cvt_pk_bf16_f32
    return c.u;
}
__device__ __forceinline__ floatx4 mfma16x32(short8 a, short8 b, floatx4 c) {
    return __builtin_amdgcn_mfma_f32_16x16x32_bf16(a, b, c, 0, 0, 0);
}
__device__ __forceinline__ floatx4 zero4() { floatx4 z = {0.f, 0.f, 0.f, 0.f}; return z; }

// Async 16B global->LDS. Per-lane lds ptr = base + lane*16B slot (HW uses
// lane0's ptr as wave base and strides lane*16 — matches our linear slots).
__device__ __forceinline__ void gload16(const ushort_t* g, ushort_t* l) {
    __builtin_amdgcn_global_load_lds(
        (const __attribute__((address_space(1))) void*)g,
        (__attribute__((address_space(3))) void*)l, 16, 0, 0);
}

// ---------------------------------------------------------------------------
// f32 -> bf16 convert (RNE), 8 elems/thread, up to 3 tensors of 4M elems.
// ---------------------------------------------------------------------------
__global__ __launch_bounds__(256) void cvt_bf16(
    const float* __restrict__ s0, const float* __restrict__ s1,
    const float* __restrict__ s2, ushort_t* __restrict__ d0,
    ushort_t* __restrict__ d1, ushort_t* __restrict__ d2)
{
    const int which = blockIdx.x >> 11;
    const int blk = blockIdx.x & 2047;
    const float* src = (which == 0) ? s0 : (which == 1) ? s1 : s2;
    ushort_t* dst = (which == 0) ? d0 : (which == 1) ? d1 : d2;
    const int i = (blk * 256 + threadIdx.x) * 8;
    float4 f0 = *(const float4*)(src + i);
    float4 f1 = *(const float4*)(src + i + 4);
    __align__(16) ushort_t t[8];
    t[0] = f2bf(f0.x); t[1] = f2bf(f0.y); t[2] = f2bf(f0.z); t[3] = f2bf(f0.w);
    t[4] = f2bf(f1.x); t[5] = f2bf(f1.y); t[6] = f2bf(f1.z); t[7] = f2bf(f1.w);
    *(uint4*)(dst + i) = *(uint4*)t;
}

// ---------------------------------------------------------------------------
// Fused convert+transpose: W[k][j] (1024x1024 f32) -> WT[j][k] bf16.
// ---------------------------------------------------------------------------
__global__ __launch_bounds__(256) void transpose_w(
    const float* __restrict__ W0, const float* __restrict__ W1,
    const float* __restrict__ W2, const float* __restrict__ W3,
    ushort_t* __restrict__ WT)
{
    __shared__ ushort_t tile[64][65];
    const float* W = (blockIdx.y == 0) ? W0 : (blockIdx.y == 1) ? W1
                   : (blockIdx.y == 2) ? W2 : W3;
    ushort_t* dst = WT + (size_t)blockIdx.y * (1024 * 1024);
    const int t = threadIdx.x;
    const int r = t >> 2, p = t & 3;
    const int j0 = (blockIdx.x & 15) << 6, k0 = (blockIdx.x >> 4) << 6;

    const float* src = W + (size_t)(k0 + r) * 1024 + j0 + p * 16;
    float4 f0 = *(const float4*)(src);
    float4 f1 = *(const float4*)(src + 4);
    float4 f2 = *(const float4*)(src + 8);
    float4 f3 = *(const float4*)(src + 12);
    ushort_t* tr = &tile[r][p * 16];
    tr[0] = f2bf(f0.x); tr[1] = f2bf(f0.y); tr[2]  = f2bf(f0.z); tr[3]  = f2bf(f0.w);
    tr[4] = f2bf(f1.x); tr[5] = f2bf(f1.y); tr[6]  = f2bf(f1.z); tr[7]  = f2bf(f1.w);
    tr[8] = f2bf(f2.x); tr[9] = f2bf(f2.y); tr[10] = f2bf(f2.z); tr[11] = f2bf(f2.w);
    tr[12] = f2bf(f3.x); tr[13] = f2bf(f3.y); tr[14] = f2bf(f3.z); tr[15] = f2bf(f3.w);
    __syncthreads();
    __align__(16) ushort_t buf[16];
#pragma unroll
    for (int i = 0; i < 16; ++i) buf[i] = tile[p * 16 + i][r];
    ushort_t* o = dst + (size_t)(j0 + r) * 1024 + k0 + p * 16;
    *(uint4*)(o)     = *(uint4*)(buf);
    *(uint4*)(o + 8) = *(uint4*)(buf + 8);
}

// ---------------------------------------------------------------------------
// Projection GEMM: C[r][c] = sum_k A[r][k]*WT[c][k] + bias[c]. 4096x1024x1024.
// 128x128 tile, BK=32, global_load_lds staging, XOR-swizzled LDS chunks.
// mode = blockIdx.z: 0: Q -> [B,H,S,64] *QSCALE; 1: K -> [B,H,S,64];
// 2: V -> [B,H,64,S].
// ---------------------------------------------------------------------------
__global__ __launch_bounds__(256) void gemm_bt(
    const ushort_t* __restrict__ A0, const ushort_t* __restrict__ A1,
    const ushort_t* __restrict__ A2, const ushort_t* __restrict__ WT,
    const float* __restrict__ b0, const float* __restrict__ b1,
    const float* __restrict__ b2,
    ushort_t* __restrict__ Dq, ushort_t* __restrict__ Dk,
    ushort_t* __restrict__ Dv)
{
    __shared__ __align__(16) ushort_t As[128 * 32];
    __shared__ __align__(16) ushort_t Bs[128 * 32];

    const int mode = blockIdx.z;
    const ushort_t* A = (mode == 0) ? A0 : (mode == 1) ? A1 : A2;
    const float* bias = (mode == 0) ? b0 : (mode == 1) ? b1 : b2;
    const ushort_t* Bt = WT + (size_t)mode * 1048576;

    const int tid = threadIdx.x;
    const int lane = tid & 63, wid = tid >> 6;
    const int quad = lane >> 4, l16 = lane & 15;
    const int wm = wid >> 1, wn = wid & 1;
    const int row0 = blockIdx.y << 7, col0 = blockIdx.x << 7;

    floatx4 acc[4][4];
#pragma unroll
    for (int i = 0; i < 4; ++i)
#pragma unroll
        for (int j = 0; j < 4; ++j) acc[i][j] = zero4();

    const int i0 = tid, i1 = 256 + tid;
    const int r0_ = i0 >> 2, c0_ = (i0 & 3) ^ (r0_ & 3);
    const int r1_ = i1 >> 2, c1_ = (i1 & 3) ^ (r1_ & 3);
    const ushort_t* gA0 = A  + (size_t)(row0 + r0_) * 1024 + c0_ * 8;
    const ushort_t* gA1 = A  + (size_t)(row0 + r1_) * 1024 + c1_ * 8;
    const ushort_t* gB0 = Bt + (size_t)(col0 + r0_) * 1024 + c0_ * 8;
    const ushort_t* gB1 = Bt + (size_t)(col0 + r1_) * 1024 + c1_ * 8;
    ushort_t* lA0 = As + i0 * 8;  ushort_t* lA1 = As + i1 * 8;
    ushort_t* lB0 = Bs + i0 * 8;  ushort_t* lB1 = Bs + i1 * 8;

    const int ra = wm * 64 + l16, rb = wn * 64 + l16;
    const int sa_off = (quad ^ (l16 & 3)) * 8;

    for (int k0 = 0; k0 < 1024; k0 += 32) {
        __syncthreads();
        gload16(gA0 + k0, lA0);
        gload16(gA1 + k0, lA1);
        gload16(gB0 + k0, lB0);
        gload16(gB1 + k0, lB1);
        __syncthreads();

        short8 af[4], bf[4];
#pragma unroll
        for (int i = 0; i < 4; ++i)
            af[i] = *(const short8*)(As + (ra + i * 16) * 32 + sa_off);
#pragma unroll
        for (int j = 0; j < 4; ++j)
            bf[j] = *(const short8*)(Bs + (rb + j * 16) * 32 + sa_off);
#pragma unroll
        for (int i = 0; i < 4; ++i)
#pragma unroll
            for (int j = 0; j < 4; ++j)
                acc[i][j] = mfma16x32(af[i], bf[j], acc[i][j]);
    }

    const float sc = (mode == 0) ? QSCALE : 1.f;
#pragma unroll
    for (int i = 0; i < 4; ++i) {
#pragma unroll
        for (int j = 0; j < 4; ++j) {
            const int c = col0 + wn * 64 + j * 16 + l16;
            const float bv = bias[c];
#pragma unroll
            for (int rr = 0; rr < 4; ++rr) {
                const int r = row0 + wm * 64 + i * 16 + quad * 4 + rr;
                const float v = (acc[i][j][rr] + bv) * sc;
                const int b = r >> 11, s = r & 2047, h = c >> 6, d = c & 63;
                if (mode <= 1) {
                    ushort_t* D = (mode == 0) ? Dq : Dk;
                    D[(((b * 16 + h) * 2048 + s) << 6) + d] = f2bf(v);
                } else {
                    Dv[(((b * 16 + h) * 64 + d) << 11) + s] = f2bf(v);
                }
            }
        }
    }
}

// ---------------------------------------------------------------------------
// Output GEMM: Dout[r][c] = sum_k A[r][k]*WoT[c][k] + bias[c], f32 out.
// 64x128 tile -> 512 blocks (2 blocks/CU).
// ---------------------------------------------------------------------------
__global__ __launch_bounds__(256) void gemm64(
    const ushort_t* __restrict__ A, const ushort_t* __restrict__ Bt,
    const float* __restrict__ bias, float* __restrict__ Dout)
{
    __shared__ __align__(16) ushort_t As[64 * 32];
    __shared__ __align__(16) ushort_t Bs[128 * 32];
    const int tid = threadIdx.x;
    const int lane = tid & 63, wid = tid >> 6;
    const int quad = lane >> 4, l16 = lane & 15;
    const int wm = wid >> 1, wn = wid & 1;
    const int row0 = blockIdx.y << 6, col0 = blockIdx.x << 7;

    floatx4 acc[2][4];
#pragma unroll
    for (int i = 0; i < 2; ++i)
#pragma unroll
        for (int j = 0; j < 4; ++j) acc[i][j] = zero4();

    const int rA = tid >> 2, cA = (tid & 3) ^ (rA & 3);
    const ushort_t* gA = A + (size_t)(row0 + rA) * 1024 + cA * 8;
    ushort_t* lA = As + tid * 8;
    const int i0 = tid, i1 = 256 + tid;
    const int rB0 = i0 >> 2, cB0 = (i0 & 3) ^ (rB0 & 3);
    const int rB1 = i1 >> 2, cB1 = (i1 & 3) ^ (rB1 & 3);
    const ushort_t* gB0 = Bt + (size_t)(col0 + rB0) * 1024 + cB0 * 8;
    const ushort_t* gB1 = Bt + (size_t)(col0 + rB1) * 1024 + cB1 * 8;
    ushort_t* lB0 = Bs + i0 * 8;  ushort_t* lB1 = Bs + i1 * 8;

    const int sa_off = (quad ^ (l16 & 3)) * 8;

    for (int k0 = 0; k0 < 1024; k0 += 32) {
        __syncthreads();
        gload16(gA + k0, lA);
        gload16(gB0 + k0, lB0);
        gload16(gB1 + k0, lB1);
        __syncthreads();

        short8 af[2], bf[4];
#pragma unroll
        for (int i = 0; i < 2; ++i)
            af[i] = *(const short8*)(As + (wm * 32 + i * 16 + l16) * 32 + sa_off);
#pragma unroll
        for (int j = 0; j < 4; ++j)
            bf[j] = *(const short8*)(Bs + (wn * 64 + j * 16 + l16) * 32 + sa_off);
#pragma unroll
        for (int i = 0; i < 2; ++i)
#pragma unroll
            for (int j = 0; j < 4; ++j)
                acc[i][j] = mfma16x32(af[i], bf[j], acc[i][j]);
    }

#pragma unroll
    for (int i = 0; i < 2; ++i)
#pragma unroll
        for (int j = 0; j < 4; ++j) {
            const int c = col0 + wn * 64 + j * 16 + l16;
            const float bv = bias[c];
#pragma unroll
            for (int rr = 0; rr < 4; ++rr) {
                const int r = row0 + wm * 32 + i * 16 + quad * 4 + rr;
                Dout[(size_t)r * 1024 + c] = acc[i][j][rr] + bv;
            }
        }
}

// ---------------------------------------------------------------------------
// Attention, Q-tile 128 (32 qrows/wave = 2 qsets), XCD-affinity grid:
// blk&31 = bh -> XCD = bh%8 (4 heads x 512KB K+V = 2MB per XCD L2).
// Each K/V LDS fragment read now feeds BOTH qsets' MFMAs (halves LDS traffic
// per output vs 64-row tile). S^T = K·Q^T: lane (l16,quad) holds
// P[qrow][kcol=g*16+quad*4+r]. PV: K=32 MFMA, slots j=0..3 <- g-block 2G,
// j=4..7 <- g-block 2G+1 on both operands. Softmax: p = exp2(min(s,80)) with
// scale folded into Q proj; P packed bf16-RNE via v_cvt_pk_bf16_f32; the
// denominator comes from a ones-B MFMA (rowsum of the EXACT bf16 P used in
// PV -> exact self-normalization, zero shuffles, C-layout reg r = qrow row).
// ---------------------------------------------------------------------------
__global__ __launch_bounds__(256, 2) void attn128(
    const ushort_t* __restrict__ Q, const ushort_t* __restrict__ K,
    const ushort_t* __restrict__ Vt, ushort_t* __restrict__ Out)
{
    __shared__ __align__(16) ushort_t Ks[64 * 64];  // [kcol][d], swizzled chunks
    __shared__ __align__(16) ushort_t Vs[64 * 64];  // [d][kcol], swizzled chunks

    const int tid = threadIdx.x;
    const int lane = tid & 63, wid = tid >> 6;
    const int quad = lane >> 4, l16 = lane & 15;
    const int blk = blockIdx.x;
    const int bh = blk & 31;          // head-major: XCD = blk%8 = bh%8
    const int q0 = (blk >> 5) << 7;   // 128 q-rows per block

    const ushort_t* Qh = Q + (size_t)bh * (2048 * 64);
    const ushort_t* Kh = K + (size_t)bh * (2048 * 64);
    const ushort_t* Vh = Vt + (size_t)bh * (64 * 2048);

    short8 qf[2][2];
#pragma unroll
    for (int s = 0; s < 2; ++s) {
        const int qr = q0 + s * 64 + wid * 16 + l16;
        qf[s][0] = *(const short8*)(Qh + (size_t)qr * 64 + quad * 8);
        qf[s][1] = *(const short8*)(Qh + (size_t)qr * 64 + 32 + quad * 8);
    }

    floatx4 o_acc[2][4], o_l[2];
#pragma unroll
    for (int s = 0; s < 2; ++s) {
        o_l[s] = zero4();
#pragma unroll
        for (int d = 0; d < 4; ++d) o_acc[s][d] = zero4();
    }

    union { uint_t u[4]; short8 s; } oc;
    oc.u[0] = oc.u[1] = oc.u[2] = oc.u[3] = 0x3F803F80u;  // bf16 1.0 x8
    const short8 ones = oc.s;

    const int i0 = tid, i1 = 256 + tid;
    const int kr0 = i0 >> 3, kc0 = (i0 & 7) ^ (kr0 & 7);
    const int kr1 = i1 >> 3, kc1 = (i1 & 7) ^ (kr1 & 7);
    const ushort_t* gK0 = Kh + (size_t)kr0 * 64 + kc0 * 8;
    const ushort_t* gK1 = Kh + (size_t)kr1 * 64 + kc1 * 8;
    const ushort_t* gV0 = Vh + (size_t)kr0 * 2048 + kc0 * 8;
    const ushort_t* gV1 = Vh + (size_t)kr1 * 2048 + kc1 * 8;
    ushort_t* lK0 = Ks + i0 * 8;  ushort_t* lK1 = Ks + i1 * 8;
    ushort_t* lV0 = Vs + i0 * 8;  ushort_t* lV1 = Vs + i1 * 8;

    const int l7 = l16 & 7;
    const int q2 = quad >> 1, q1 = (quad & 1) * 4;

    for (int kt = 0; kt < 2048; kt += 64) {
        __syncthreads();
        gload16(gK0 + (size_t)kt * 64, lK0);
        gload16(gK1 + (size_t)kt * 64, lK1);
        gload16(gV0 + kt, lV0);
        gload16(gV1 + kt, lV1);
        __syncthreads();

        // S^T: each kf read feeds both qsets
        floatx4 sa[2][4];
#pragma unroll
        for (int g = 0; g < 4; ++g) {
            const int row = g * 16 + l16;  // kcol
            const short8 kf0 = *(const short8*)(Ks + row * 64 + ((quad ^ l7) * 8));
            const short8 kf1 = *(const short8*)(Ks + row * 64 + (((quad + 4) ^ l7) * 8));
#pragma unroll
            for (int s = 0; s < 2; ++s) {
                sa[s][g] = mfma16x32(kf0, qf[s][0], zero4());
                sa[s][g] = mfma16x32(kf1, qf[s][1], sa[s][g]);
            }
        }

        // softmax + PV: two g-blocks per K=32 MFMA; V reads shared by qsets
#pragma unroll
        for (int G = 0; G < 2; ++G) {
            short8 pf[2];
#pragma unroll
            for (int s = 0; s < 2; ++s) {
                float e[8];
#pragma unroll
                for (int t = 0; t < 8; ++t) {
                    const int g = G * 2 + (t >> 2), r = t & 3;
                    e[t] = __builtin_amdgcn_exp2f(fminf(sa[s][g][r], 80.f));
                }
                union { uint_t u[4]; short8 s8; } pc;
                pc.u[0] = pack_bf2(e[0], e[1]);
                pc.u[1] = pack_bf2(e[2], e[3]);
                pc.u[2] = pack_bf2(e[4], e[5]);
                pc.u[3] = pack_bf2(e[6], e[7]);
                pf[s] = pc.s8;
                o_l[s] = mfma16x32(pf[s], ones, o_l[s]);  // exact denominator
            }

            const int ch0 = ((4 * G + q2) ^ l7) * 8;
            const int ch1 = ((4 * G + 2 + q2) ^ l7) * 8;
#pragma unroll
            for (int db = 0; db < 4; ++db) {
                const int vbase = (db * 16 + l16) * 64 + q1;
                const uint2 v0 = *(const uint2*)(Vs + vbase + ch0);
                const uint2 v1 = *(const uint2*)(Vs + vbase + ch1);
                union { uint_t u[4]; short8 s8; } vc;
                vc.u[0] = v0.x; vc.u[1] = v0.y; vc.u[2] = v1.x; vc.u[3] = v1.y;
#pragma unroll
                for (int s = 0; s < 2; ++s)
                    o_acc[s][db] = mfma16x32(pf[s], vc.s8, o_acc[s][db]);
            }
        }
    }

    const int b = bh >> 4, h = bh & 15;
#pragma unroll
    for (int s = 0; s < 2; ++s) {
        const int s0 = q0 + s * 64 + wid * 16 + quad * 4;
#pragma unroll
        for (int r = 0; r < 4; ++r) {
            const float inv = 1.f / o_l[s][r];   // rowsum for qrow quad*4+r
#pragma unroll
            for (int db = 0; db < 4; ++db) {
                const float v = o_acc[s][db][r] * inv;
                Out[(size_t)(b * 2048 + s0 + r) * 1024 + h * 64 + db * 16 + l16] = f2bf(v);
            }
        }
    }
}

// ---------------------------------------------------------------------------
// Launch. Both paths: tp -> cvt3 -> gemm z=3 (1536 blk) -> attn128 -> gemm64.
//  big (>=64MiB): WT@0 Qb@8M Kb@16M Vb@24M Qp@32M Kp@40M Vtp@48M An@56M
//  small (40MiB): WT@0 buf1@8M buf2@16M Qp@24M Kp@32M; d_out (16MB) doubles
//    as scratch: lo 8MB = V bf16 input, hi 8MB = Vtp — both dead before
//    gemm64 overwrites d_out with the final f32 result.
// ---------------------------------------------------------------------------
extern "C" void kernel_launch(void* const* d_in, const int* in_sizes, int n_in,
                              void* d_out, int out_size, void* d_ws, size_t ws_size,
                              hipStream_t stream) {
    const float* queries = (const float*)d_in[0];
    const float* keys    = (const float*)d_in[1];
    const float* values  = (const float*)d_in[2];
    const float* Wq = (const float*)d_in[3];
    const float* bq = (const float*)d_in[4];
    const float* Wk = (const float*)d_in[5];
    const float* bk = (const float*)d_in[6];
    const float* Wv = (const float*)d_in[7];
    const float* bv = (const float*)d_in[8];
    const float* Wo = (const float*)d_in[9];
    const float* bo = (const float*)d_in[10];
    float* out = (float*)d_out;

    char* ws = (char*)d_ws;
    const size_t MB = 1024 * 1024;
    ushort_t* WT = (ushort_t*)(ws);
    const ushort_t* WoT = WT + 3 * 1048576;
    dim3 tb(256);

    transpose_w<<<dim3(256, 4), tb, 0, stream>>>(Wq, Wk, Wv, Wo, WT);

    if (ws_size >= 64 * MB) {
        ushort_t* Qb  = (ushort_t*)(ws + 8 * MB);
        ushort_t* Kb  = (ushort_t*)(ws + 16 * MB);
        ushort_t* Vb  = (ushort_t*)(ws + 24 * MB);
        ushort_t* Qp  = (ushort_t*)(ws + 32 * MB);
        ushort_t* Kp  = (ushort_t*)(ws + 40 * MB);
        ushort_t* Vtp = (ushort_t*)(ws + 48 * MB);
        ushort_t* An  = (ushort_t*)(ws + 56 * MB);
        cvt_bf16<<<dim3(6144), tb, 0, stream>>>(queries, keys, values, Qb, Kb, Vb);
        gemm_bt<<<dim3(8, 32, 3), tb, 0, stream>>>(Qb, Kb, Vb, WT,
            bq, bk, bv, Qp, Kp, Vtp);
        attn128<<<dim3(512), tb, 0, stream>>>(Qp, Kp, Vtp, An);
        gemm64<<<dim3(8, 64), tb, 0, stream>>>(An, WoT, bo, out);
    } else {
        ushort_t* buf1 = (ushort_t*)(ws + 8 * MB);
        ushort_t* buf2 = (ushort_t*)(ws + 16 * MB);
        ushort_t* Qp   = (ushort_t*)(ws + 24 * MB);
        ushort_t* Kp   = (ushort_t*)(ws + 32 * MB);
        ushort_t* Vb   = (ushort_t*)d_out;              // d_out lo 8MB
        ushort_t* Vtp  = (ushort_t*)d_out + 4194304;    // d_out hi 8MB
        cvt_bf16<<<dim3(6144), tb, 0, stream>>>(queries, keys, values, buf1, buf2, Vb);
        gemm_bt<<<dim3(8, 32, 3), tb, 0, stream>>>(buf1, buf2, Vb, WT,
            bq, bk, bv, Qp, Kp, Vtp);
        attn128<<<dim3(512), tb, 0, stream>>>(Qp, Kp, Vtp, buf1);
        gemm64<<<dim3(8, 64), tb, 0, stream>>>(buf1, WoT, bo, out);
    }
}